// Round 2
// baseline (1073.626 us; speedup 1.0000x reference)
//
#include <hip/hip_runtime.h>
#include <string.h>

typedef unsigned short u16;
typedef __bf16 bf16_t;
typedef bf16_t bf16x8 __attribute__((ext_vector_type(8)));
typedef float f32x4 __attribute__((ext_vector_type(4)));
typedef u16 u16x4 __attribute__((ext_vector_type(4)));

#define MODE_PLAIN 0
#define MODE_QP 1
#define MODE_SPLITN 2
#define MODE_EPI 3
#define MODE_BIASF32 4

__device__ __forceinline__ float bf2f(u16 u) {
  unsigned int x = ((unsigned int)u) << 16;
  return __builtin_bit_cast(float, x);
}
__device__ __forceinline__ u16 f2bf(float f) {
  unsigned int x = __builtin_bit_cast(unsigned int, f);
  x += 0x7fffu + ((x >> 16) & 1u);
  return (u16)(x >> 16);
}

__device__ __forceinline__ void gload_lds16(const void* g, void* l) {
  __builtin_amdgcn_global_load_lds(
      (const __attribute__((address_space(1))) void*)g,
      (__attribute__((address_space(3))) void*)l, 16, 0, 0);
}

struct GemmP {
  const u16* A0; const u16* A1;       // bf16 A (z-select) — used if Af0==nullptr
  const float* Af0; const float* Af1; // f32 A (z-select) — converted at stage time
  const u16* B;  long bz;             // bf16 B — used if Bf==nullptr
  const float* Bf;                    // f32 B
  int lda, ldb, K, mode;              // lda/ldb in elements of respective dtype
  u16* C; long cz; int ldc;
  u16* C2;                            // P for QP mode
  const u16* E; long ez;              // bf16 extra operand (U) for EPI
  const float* Ef;                    // f32 extra operand (feat) — overrides E
  const float* biasf;                 // BIASF32
  float* Cf;                          // BIASF32 output
  float c1, c2;                       // EPI: out = E + c1*sigmoid(c2*acc)
};

// C[m][n] = sum_k A[m][k] * B[n][k]   (A: [M,K], B: [N,K]; M,N %128==0, K%64==0)
__global__ __launch_bounds__(256) void gemm_nt(GemmP p) {
  __shared__ u16 smem[2 * 128 * 64];   // A tile then B tile, 16B chunks, XOR swizzle
  const int tid = threadIdx.x;
  const int lane = tid & 63, wave = tid >> 6;
  const int z = blockIdx.z;
  const long tileM = (long)blockIdx.y * 128;
  const long tileN = (long)blockIdx.x * 128;
  u16* ldsA = smem;
  u16* ldsB = smem + 128 * 64;

  const u16* A = (z == 0) ? p.A0 : p.A1;
  const u16* B = p.B + (long)z * p.bz;
  const float* Af = (z == 0) ? p.Af0 : p.Af1;
  const float* Bf = p.Bf;

  // bf16 staging: issue j covers rows [j*32, j*32+32); lane l -> row j*32+wave*8+l/8
  const int srow = wave * 8 + (lane >> 3);
  const int ssc = lane & 7;
  long aoff[4], boff[4];
#pragma unroll
  for (int j = 0; j < 4; ++j) {
    int r = j * 32 + srow;
    int c = ssc ^ (r & 7);               // LDS[r][ssc] holds global chunk c
    aoff[j] = ((tileM + r) * (long)p.lda + c * 8) * 2;
    boff[j] = ((tileN + r) * (long)p.ldb + c * 8) * 2;
  }
  // f32 staging: thread -> (row = i*16 + tid/16, float4-col = tid%16)
  const int frow = tid >> 4, fcol = tid & 15;

  const int r15 = lane & 15, q = lane >> 4;
  const int wm = (wave & 1) * 64, wn = (wave >> 1) * 64;

  f32x4 acc[4][4];
#pragma unroll
  for (int i = 0; i < 4; ++i)
#pragma unroll
    for (int j = 0; j < 4; ++j) { f32x4 zz = {0.f, 0.f, 0.f, 0.f}; acc[i][j] = zz; }

  const int K64 = p.K >> 6;
  for (int kt = 0; kt < K64; ++kt) {
    __syncthreads();   // prior tile fully consumed
    if (Af) {
#pragma unroll
      for (int i = 0; i < 8; ++i) {
        int r = i * 16 + frow;
        f32x4 v = *(const f32x4*)(Af + (tileM + r) * (long)p.lda + (long)kt * 64 + fcol * 4);
        int sc = (fcol >> 1) ^ (r & 7);
        u16x4 o; o[0] = f2bf(v[0]); o[1] = f2bf(v[1]); o[2] = f2bf(v[2]); o[3] = f2bf(v[3]);
        *(u16x4*)(ldsA + (r * 8 + sc) * 8 + (fcol & 1) * 4) = o;
      }
    } else {
#pragma unroll
      for (int j = 0; j < 4; ++j)
        gload_lds16((const char*)A + aoff[j] + (long)kt * 128,
                    (char*)ldsA + (j * 256 + wave * 64) * 16);
    }
    if (Bf) {
#pragma unroll
      for (int i = 0; i < 8; ++i) {
        int r = i * 16 + frow;
        f32x4 v = *(const f32x4*)(Bf + (tileN + r) * (long)p.ldb + (long)kt * 64 + fcol * 4);
        int sc = (fcol >> 1) ^ (r & 7);
        u16x4 o; o[0] = f2bf(v[0]); o[1] = f2bf(v[1]); o[2] = f2bf(v[2]); o[3] = f2bf(v[3]);
        *(u16x4*)(ldsB + (r * 8 + sc) * 8 + (fcol & 1) * 4) = o;
      }
    } else {
#pragma unroll
      for (int j = 0; j < 4; ++j)
        gload_lds16((const char*)B + boff[j] + (long)kt * 128,
                    (char*)ldsB + (j * 256 + wave * 64) * 16);
    }
    __syncthreads();   // staging visible (compiler drains vmcnt/lgkmcnt)
#pragma unroll
    for (int ks = 0; ks < 2; ++ks) {
      bf16x8 af[4], bfr[4];
#pragma unroll
      for (int mt = 0; mt < 4; ++mt) {
        int row = wm + mt * 16 + r15;
        int sc = (ks * 4 + q) ^ (r15 & 7);
        af[mt] = *(const bf16x8*)(ldsA + (row * 8 + sc) * 8);
      }
#pragma unroll
      for (int nt = 0; nt < 4; ++nt) {
        int row = wn + nt * 16 + r15;
        int sc = (ks * 4 + q) ^ (r15 & 7);
        bfr[nt] = *(const bf16x8*)(ldsB + (row * 8 + sc) * 8);
      }
#pragma unroll
      for (int mt = 0; mt < 4; ++mt)
#pragma unroll
        for (int nt = 0; nt < 4; ++nt)
          acc[mt][nt] = __builtin_amdgcn_mfma_f32_16x16x32_bf16(af[mt], bfr[nt], acc[mt][nt], 0, 0, 0);
    }
  }

  // epilogue — C/D layout: col = lane&15, row = (lane>>4)*4 + reg  [m89-verified]
  const int mode = p.mode;
  u16* Cz = p.C + (long)z * p.cz;
  const u16* Ez = p.E + (long)z * p.ez;
#pragma unroll
  for (int mt = 0; mt < 4; ++mt) {
#pragma unroll
    for (int nt = 0; nt < 4; ++nt) {
#pragma unroll
      for (int r = 0; r < 4; ++r) {
        long row = tileM + wm + mt * 16 + q * 4 + r;
        long col = tileN + wn + nt * 16 + r15;
        float v = acc[mt][nt][r];
        if (mode == MODE_PLAIN) {
          Cz[row * p.ldc + col] = f2bf(v);
        } else if (mode == MODE_QP) {
          long b = row >> 12, i = row & 4095;
          long addr = i * 1536 + b * 512 + col;
          p.C[addr] = f2bf(v);
          float s = (b == 0) ? 1.f : -0.5f;
          p.C2[addr] = f2bf(s * v);
        } else if (mode == MODE_SPLITN) {
          long b = col >> 12, i = col & 4095;
          p.C[b * 2097152 + row * 4096 + i] = f2bf(v);
        } else if (mode == MODE_EPI) {
          float e = p.Ef ? p.Ef[row * 512 + col] : bf2f(Ez[row * 512 + col]);
          float s = 1.f / (1.f + __expf(-(p.c2 * v)));
          Cz[row * 512 + col] = f2bf(e + p.c1 * s);
        } else {  // MODE_BIASF32
          p.Cf[row * 512 + col] = v + p.biasf[col];
        }
      }
    }
  }
}

// ---- small utility kernels ----

__global__ __launch_bounds__(256) void pack_m2_k(const float* wy, u16* M2) {
  int idx = blockIdx.x * 256 + threadIdx.x;   // 0..262143
  int i = idx >> 9, j = idx & 511;
  M2[(long)i * 1024 + j] = f2bf(wy[idx]);                  // [wy | wy^T]
  M2[(long)i * 1024 + 512 + j] = f2bf(wy[(long)j * 512 + i]);
}

__global__ __launch_bounds__(256) void init_ycat_k(const float* y, const float* feat, u16* Ycat) {
  long idx = (long)blockIdx.x * 256 + threadIdx.x;  // float4 units; 524288 total
  f32x4 a = ((const f32x4*)y)[idx];
  f32x4 f = ((const f32x4*)feat)[idx];
  u16x4 ua, uf;
#pragma unroll
  for (int i = 0; i < 4; ++i) { ua[i] = f2bf(a[i]); uf[i] = f2bf(f[i]); }
  ((u16x4*)Ycat)[idx] = ua;
  ((u16x4*)Ycat)[idx + 524288] = uf;
  ((u16x4*)Ycat)[idx + 1048576] = uf;
}

__global__ __launch_bounds__(256) void transpose_k(const u16* in, u16* out, long inz, long outz) {
  // in: [4096][512] bf16, out: [512][4096] bf16, 64x64 tiles
  __shared__ u16 t[64][68];
  const u16* src = in + (long)blockIdx.z * inz;
  u16* dst = out + (long)blockIdx.z * outz;
  int tid = threadIdx.x;
  int tr = tid >> 4, tc = (tid & 15) * 4;
  long r0 = (long)blockIdx.y * 64, c0 = (long)blockIdx.x * 64;
#pragma unroll
  for (int i = 0; i < 4; ++i) {
    int r = i * 16 + tr;
    uint2 v = *(const uint2*)(src + (r0 + r) * 512 + c0 + tc);
    t[r][tc] = (u16)(v.x & 0xffff); t[r][tc + 1] = (u16)(v.x >> 16);
    t[r][tc + 2] = (u16)(v.y & 0xffff); t[r][tc + 3] = (u16)(v.y >> 16);
  }
  __syncthreads();
#pragma unroll
  for (int i = 0; i < 4; ++i) {
    int r = i * 16 + tr;
    unsigned int a0 = t[tc + 0][r], a1 = t[tc + 1][r], a2 = t[tc + 2][r], a3 = t[tc + 3][r];
    uint2 v; v.x = a0 | (a1 << 16); v.y = a2 | (a3 << 16);
    *(uint2*)(dst + (c0 + r) * 4096 + r0 + tc) = v;
  }
}

__device__ __forceinline__ float waveRedSum(float v) {
#pragma unroll
  for (int o = 32; o > 0; o >>= 1) v += __shfl_down(v, o, 64);
  return v;
}
__device__ __forceinline__ float waveRedMax(float v) {
#pragma unroll
  for (int o = 32; o > 0; o >>= 1) v = fmaxf(v, __shfl_down(v, o, 64));
  return v;
}

__global__ __launch_bounds__(256) void l2norm_k(const u16* Ycat, u16* pb) {
  __shared__ float red[4];
  int i = blockIdx.x, b = blockIdx.y, t = threadIdx.x;
  const u16* row = Ycat + ((long)b * 4096 + (long)i) * 512;
  unsigned int v = *(const unsigned int*)(row + 2 * t);
  float x0 = bf2f((u16)(v & 0xffff)), x1 = bf2f((u16)(v >> 16));
  float w = waveRedSum(x0 * x0 + x1 * x1);
  if ((t & 63) == 0) red[t >> 6] = w;
  __syncthreads();
  float tot = red[0] + red[1] + red[2] + red[3];
  float inv = 1.f / fmaxf(sqrtf(tot), 1e-12f);
  unsigned int o = (unsigned int)f2bf(x0 * inv) | ((unsigned int)f2bf(x1 * inv) << 16);
  *(unsigned int*)(pb + (long)i * 1536 + b * 512 + 2 * t) = o;
}

__global__ __launch_bounds__(256) void logsoftmax_k(const float* lg, float* out) {
  __shared__ float red[4];
  int i = blockIdx.x, t = threadIdx.x;
  const float* row = lg + (long)i * 512;
  float a = row[t], b2 = row[t + 256];
  float m = waveRedMax(fmaxf(a, b2));
  if ((t & 63) == 0) red[t >> 6] = m;
  __syncthreads();
  float M = fmaxf(fmaxf(red[0], red[1]), fmaxf(red[2], red[3]));
  __syncthreads();
  float w = waveRedSum(__expf(a - M) + __expf(b2 - M));
  if ((t & 63) == 0) red[t >> 6] = w;
  __syncthreads();
  float S = red[0] + red[1] + red[2] + red[3];
  float lse = M + __logf(S);
  out[(long)i * 512 + t] = a - lse;
  out[(long)i * 512 + t + 256] = b2 - lse;
}

extern "C" void kernel_launch(void* const* d_in, const int* in_sizes, int n_in,
                              void* d_out, int out_size, void* d_ws, size_t ws_size,
                              hipStream_t stream) {
  const float* feat = (const float*)d_in[0];
  const float* adj  = (const float*)d_in[1];
  const float* adj1 = (const float*)d_in[2];
  const float* y    = (const float*)d_in[3];
  const float* wy   = (const float*)d_in[4];
  const float* w2w  = (const float*)d_in[5];
  const float* w2b  = (const float*)d_in[6];
  (void)in_sizes; (void)n_in; (void)out_size; (void)ws_size;

  char* ws = (char*)d_ws;
  size_t off = 0;
  auto alloc = [&](size_t bytes) -> void* {
    void* r = ws + off; off += (bytes + 255) & ~(size_t)255; return r;
  };
  u16* M2   = (u16*)alloc(512L * 1024 * 2);
  u16* Wsum = (u16*)alloc(512L * 512 * 2);
  u16* Ycat = (u16*)alloc(3L * 4096 * 512 * 2);
  u16* Q    = (u16*)alloc(4096L * 1536 * 2);
  u16* P    = (u16*)alloc(4096L * 1536 * 2);
  u16* Tt   = (u16*)alloc(3L * 512 * 4096 * 2);
  u16* Zt   = (u16*)alloc(2L * 512 * 4096 * 2);
  u16* t11  = (u16*)alloc(4096L * 4096 * 2);
  u16* U    = (u16*)alloc(2L * 4096 * 512 * 2);
  u16* pb = Q;                  // reuse: Q dead after layer-2 Gram
  float* logits = (float*)Zt;   // reuse: Zt dead after layer-2 U gemm (8MB)
  const long S = 2097152;       // 4096*512

  pack_m2_k<<<1024, 256, 0, stream>>>(wy, M2);
  init_ycat_k<<<2048, 256, 0, stream>>>(y, feat, Ycat);

  { GemmP p = {}; p.A0 = p.A1 = M2; p.B = M2; p.lda = 1024; p.ldb = 1024; p.K = 1024;
    p.mode = MODE_PLAIN; p.C = Wsum; p.ldc = 512;
    gemm_nt<<<dim3(4, 4, 1), 256, 0, stream>>>(p); }           // Wsum = wy@wy^T + wy^T@wy

  for (int L = 0; L < 2; ++L) {
    { GemmP p = {}; p.A0 = p.A1 = Ycat; p.B = M2 + 512; p.lda = 512; p.ldb = 1024; p.K = 512;
      p.mode = MODE_QP; p.C = Q; p.C2 = P;
      gemm_nt<<<dim3(4, 96, 1), 256, 0, stream>>>(p); }        // Q=[yw|z1w|z2w], P scaled
    { GemmP p = {}; p.A0 = p.A1 = Wsum; p.B = Ycat; p.lda = 512; p.ldb = 512; p.K = 512;
      p.mode = MODE_SPLITN; p.C = Tt;
      gemm_nt<<<dim3(96, 4, 1), 256, 0, stream>>>(p); }        // Tt[b] = (Ycat[b]@Wsum)^T
    { GemmP p = {}; p.A0 = p.A1 = P; p.B = Q; p.lda = 1536; p.ldb = 1536; p.K = 1536;
      p.mode = MODE_PLAIN; p.C = t11; p.ldc = 4096;
      gemm_nt<<<dim3(32, 32, 1), 256, 0, stream>>>(p); }       // temp11 = P@Q^T
    transpose_k<<<dim3(8, 64, 2), 256, 0, stream>>>(Ycat + S, Zt, S, S);  // z1^T, z2^T
    { GemmP p = {}; p.Af0 = adj; p.Af1 = adj1; p.B = Zt; p.bz = S; p.lda = 4096; p.ldb = 4096;
      p.K = 4096; p.mode = MODE_PLAIN; p.C = U; p.cz = S; p.ldc = 512;
      gemm_nt<<<dim3(4, 32, 2), 256, 0, stream>>>(p); }        // U0=adj@z1, U1=adj1@z2
    { GemmP p = {}; p.A0 = p.A1 = t11; p.B = Tt; p.lda = 4096; p.ldb = 4096; p.K = 4096;
      p.mode = MODE_EPI; p.Ef = feat; p.c1 = -0.5f; p.c2 = 1.f; p.C = Ycat; p.cz = 0;
      gemm_nt<<<dim3(4, 32, 1), 256, 0, stream>>>(p); }        // y = feat - 0.5*sig(t11@t12)
    { GemmP p = {}; p.A0 = p.A1 = t11; p.B = Tt + S; p.bz = S; p.lda = 4096; p.ldb = 4096;
      p.K = 4096; p.mode = MODE_EPI; p.E = U; p.ez = S; p.c1 = -0.25f; p.c2 = -1.f;
      p.C = Ycat + S; p.cz = S;
      gemm_nt<<<dim3(4, 32, 2), 256, 0, stream>>>(p); }        // z = U - 0.25*sig(-t11@t)
  }

  l2norm_k<<<dim3(4096, 3, 1), 256, 0, stream>>>(Ycat, pb);
  { GemmP p = {}; p.A0 = p.A1 = pb; p.Bf = w2w; p.lda = 1536; p.ldb = 1536; p.K = 1536;
    p.mode = MODE_BIASF32; p.Cf = logits; p.biasf = w2b;
    gemm_nt<<<dim3(4, 32, 1), 256, 0, stream>>>(p); }          // logits = p@w2w^T + b
  logsoftmax_k<<<4096, 256, 0, stream>>>(logits, (float*)d_out);
}